// Round 1
// baseline (756.329 us; speedup 1.0000x reference)
//
#include <hip/hip_runtime.h>

typedef _Float16 f16;
typedef f16 f16x8 __attribute__((ext_vector_type(8)));
typedef float f32x4 __attribute__((ext_vector_type(4)));

#define MFMA16(a, b, c) __builtin_amdgcn_mfma_f32_16x16x32_f16((a), (b), (c), 0, 0, 0)

static __device__ __forceinline__ f16x8 cvt8(const float* __restrict__ p) {
    f32x4 p0 = *(const f32x4*)p;
    f32x4 p1 = *(const f32x4*)(p + 4);
    f16x8 a;
    a[0] = (f16)p0[0]; a[1] = (f16)p0[1]; a[2] = (f16)p0[2]; a[3] = (f16)p0[3];
    a[4] = (f16)p1[0]; a[5] = (f16)p1[1]; a[6] = (f16)p1[2]; a[7] = (f16)p1[3];
    return a;
}

// Repack a [K x 128] f32 weight matrix into B-fragment order for
// mfma_f32_16x16x32_f16: frag (kt, nt), lane holds B[kt*32+quad*8+j][nt*16+col].
__global__ __launch_bounds__(256) void k_repack(const float* __restrict__ W,
                                                f16* __restrict__ out, int KT) {
    int idx = blockIdx.x * blockDim.x + threadIdx.x;
    int total = KT * 8 * 64;
    if (idx >= total) return;
    int lane = idx & 63;
    int frag = idx >> 6;
    int nt = frag & 7;
    int kt = frag >> 3;
    int colx = lane & 15, quad = lane >> 4;
    f16* o = out + (size_t)idx * 8;
    const float* wb = W + (size_t)(kt * 32 + quad * 8) * 128 + nt * 16 + colx;
#pragma unroll
    for (int j = 0; j < 8; j++) o[j] = (f16)wb[(size_t)j * 128];
}

__global__ __launch_bounds__(256) void k_count(const int* __restrict__ ei, int E,
                                               int* __restrict__ degv) {
    int e = blockIdx.x * blockDim.x + threadIdx.x;
    if (e < E) atomicAdd(&degv[ei[E + e]], 1);
}

__global__ __launch_bounds__(256) void k_nodes(const int* __restrict__ dep, int N,
                                               int* __restrict__ dcnt, int* __restrict__ dlist) {
    int v = blockIdx.x * blockDim.x + threadIdx.x;
    if (v >= N) return;
    int d = dep[v];
    if (d >= 1 && d <= 4) {
        int p = atomicAdd(&dcnt[d - 1], 1);
        dlist[(size_t)(d - 1) * N + p] = v;
    }
}

__global__ __launch_bounds__(1024) void k_scan(const int* __restrict__ degv,
                                               int* __restrict__ rowp, int N, int E) {
    __shared__ int lds[1024];
    int t = threadIdx.x;
    int chunk = (N + 1023) >> 10;
    int s0 = t * chunk;
    int s1 = s0 + chunk; if (s1 > N) s1 = N;
    int s = 0;
    for (int i = s0; i < s1; i++) s += degv[i];
    lds[t] = s;
    __syncthreads();
    for (int d = 1; d < 1024; d <<= 1) {
        int v = (t >= d) ? lds[t - d] : 0;
        __syncthreads();
        lds[t] += v;
        __syncthreads();
    }
    int off = (t == 0) ? 0 : lds[t - 1];
    for (int i = s0; i < s1; i++) { rowp[i] = off; off += degv[i]; }
    if (t == 0) rowp[N] = E;
}

__global__ __launch_bounds__(256) void k_scatter(const int* __restrict__ ei,
                                                 const float* __restrict__ eattr,
                                                 const int* __restrict__ rowp,
                                                 int* __restrict__ cur,
                                                 int* __restrict__ esrc,
                                                 float* __restrict__ eso, int E) {
    int e = blockIdx.x * blockDim.x + threadIdx.x;
    if (e >= E) return;
    int s = ei[e], d = ei[E + e];
    int p = rowp[d] + atomicAdd(&cur[d], 1);
    esrc[p] = s;
    eso[p] = eattr[e];
}

// h = x @ pw + pb ;  t = h @ mw1[0:128] + mb1   (one wave = 16 node rows)
__global__ __launch_bounds__(256) void k_proj(const float* __restrict__ x,
                                              const f16* __restrict__ pwp,
                                              const f16* __restrict__ mw1p,
                                              const float* __restrict__ pb,
                                              const float* __restrict__ mb1,
                                              float* __restrict__ h,
                                              f16* __restrict__ t, int N) {
    __shared__ __align__(16) f16 lds[4][16 * 136];
    int lane = threadIdx.x & 63, w = threadIdx.x >> 6;
    int colx = lane & 15, quad = lane >> 4;
    int base = (blockIdx.x * 4 + w) * 16;
    int arow = base + colx;
    int u = arow < N ? arow : N - 1;

    f32x4 c1[8];
#pragma unroll
    for (int nt = 0; nt < 8; nt++) c1[nt] = (f32x4){0.f, 0.f, 0.f, 0.f};
#pragma unroll
    for (int kt = 0; kt < 4; kt++) {
        f16x8 a = cvt8(x + (size_t)u * 128 + kt * 32 + quad * 8);
#pragma unroll
        for (int nt = 0; nt < 8; nt++) {
            f16x8 b = *(const f16x8*)(pwp + ((size_t)(kt * 8 + nt) * 64 + lane) * 8);
            c1[nt] = MFMA16(a, b, c1[nt]);
        }
    }
#pragma unroll
    for (int nt = 0; nt < 8; nt++) {
        float bias = pb[nt * 16 + colx];
#pragma unroll
        for (int reg = 0; reg < 4; reg++) {
            int row = quad * 4 + reg;
            int node = base + row;
            float v = c1[nt][reg] + bias;
            lds[w][row * 136 + nt * 16 + colx] = (f16)v;
            if (node < N) h[(size_t)node * 128 + nt * 16 + colx] = v;
        }
    }
    __syncthreads();
    f32x4 c2[8];
#pragma unroll
    for (int nt = 0; nt < 8; nt++) c2[nt] = (f32x4){0.f, 0.f, 0.f, 0.f};
#pragma unroll
    for (int kt = 0; kt < 4; kt++) {
        f16x8 a = *(const f16x8*)&lds[w][colx * 136 + kt * 32 + quad * 8];
#pragma unroll
        for (int nt = 0; nt < 8; nt++) {
            f16x8 b = *(const f16x8*)(mw1p + ((size_t)(kt * 8 + nt) * 64 + lane) * 8);
            c2[nt] = MFMA16(a, b, c2[nt]);
        }
    }
#pragma unroll
    for (int nt = 0; nt < 8; nt++) {
        float bias = mb1[nt * 16 + colx];
#pragma unroll
        for (int reg = 0; reg < 4; reg++) {
            int node = base + quad * 4 + reg;
            if (node < N) t[(size_t)node * 128 + nt * 16 + colx] = (f16)(c2[nt][reg] + bias);
        }
    }
}

// One wave per destination node of this depth: build hidden A-tiles (16 edges),
// msg = relu(hidden @ mw2 + mb2), masked row-reduce into agg, mean-divide.
__global__ __launch_bounds__(256) void k_msg(const f16* __restrict__ t,
                                             const float* __restrict__ mw1,
                                             const float* __restrict__ mb2,
                                             const f16* __restrict__ mw2p,
                                             const int* __restrict__ rowp,
                                             const int* __restrict__ esrc,
                                             const float* __restrict__ eso,
                                             const int* __restrict__ dlist,
                                             const int* __restrict__ dcnt, int dIdx,
                                             f16* __restrict__ agg, int N) {
    int lane = threadIdx.x & 63;
    int wid = blockIdx.x * 4 + (threadIdx.x >> 6);
    int cnt = dcnt[dIdx];
    if (wid >= cnt) return;
    int colx = lane & 15, quad = lane >> 4;
    int u = dlist[(size_t)dIdx * N + wid];
    int e0 = rowp[u], e1 = rowp[u + 1];

    const float* w1r = mw1 + 128 * 128;  // row 128 of mw1: edge-attr weights
    float w1f[4][8];
#pragma unroll
    for (int kt = 0; kt < 4; kt++) {
        f32x4 q0 = *(const f32x4*)(w1r + kt * 32 + quad * 8);
        f32x4 q1 = *(const f32x4*)(w1r + kt * 32 + quad * 8 + 4);
        w1f[kt][0] = q0[0]; w1f[kt][1] = q0[1]; w1f[kt][2] = q0[2]; w1f[kt][3] = q0[3];
        w1f[kt][4] = q1[0]; w1f[kt][5] = q1[1]; w1f[kt][6] = q1[2]; w1f[kt][7] = q1[3];
    }
    float mb2v[8];
#pragma unroll
    for (int nt = 0; nt < 8; nt++) mb2v[nt] = mb2[nt * 16 + colx];

    float aggv[8] = {0.f, 0.f, 0.f, 0.f, 0.f, 0.f, 0.f, 0.f};

    for (int bs = e0; bs < e1; bs += 16) {
        int es = bs + colx;
        if (es >= e1) es = e0;  // safe dummy; masked in reduction
        int src = esrc[es];
        float ea = eso[es];
        const f16* trow = t + (size_t)src * 128;
        f16x8 afr[4];
#pragma unroll
        for (int kt = 0; kt < 4; kt++) {
            f16x8 tv = *(const f16x8*)(trow + kt * 32 + quad * 8);
            f16x8 hv;
#pragma unroll
            for (int j = 0; j < 8; j++) {
                float v = (float)tv[j] + ea * w1f[kt][j];
                hv[j] = (f16)fmaxf(v, 0.f);
            }
            afr[kt] = hv;
        }
#pragma unroll
        for (int nt = 0; nt < 8; nt++) {
            f32x4 c = (f32x4){0.f, 0.f, 0.f, 0.f};
#pragma unroll
            for (int kt = 0; kt < 4; kt++) {
                f16x8 b = *(const f16x8*)(mw2p + ((size_t)(kt * 8 + nt) * 64 + lane) * 8);
                c = MFMA16(afr[kt], b, c);
            }
            float s = 0.f;
#pragma unroll
            for (int reg = 0; reg < 4; reg++) {
                if (bs + quad * 4 + reg < e1) s += fmaxf(c[reg] + mb2v[nt], 0.f);
            }
            aggv[nt] += s;
        }
    }
    int deg = e1 - e0;
    float inv = 1.f / (float)(deg > 1 ? deg : 1);
#pragma unroll
    for (int nt = 0; nt < 8; nt++) {
        float s = aggv[nt];
        s += __shfl_xor(s, 16, 64);
        s += __shfl_xor(s, 32, 64);
        if (quad == 0) agg[(size_t)u * 128 + nt * 16 + colx] = (f16)(s * inv);
    }
}

// One wave = 16 nodes of this depth: h_new = relu(relu([h,agg]@uw1+ub1)@uw2+ub2),
// write h (f32) and refresh t = h_new @ mw1 + mb1.
__global__ __launch_bounds__(256) void k_upd(float* __restrict__ h, f16* __restrict__ t,
                                             const f16* __restrict__ agg,
                                             const f16* __restrict__ uw1p,
                                             const f16* __restrict__ uw2p,
                                             const f16* __restrict__ mw1p,
                                             const float* __restrict__ ub1,
                                             const float* __restrict__ ub2,
                                             const float* __restrict__ mb1,
                                             const int* __restrict__ dlist,
                                             const int* __restrict__ dcnt, int dIdx, int N) {
    __shared__ __align__(16) f16 lds[4][2][16 * 136];
    int cnt = dcnt[dIdx];
    if ((int)blockIdx.x * 64 >= cnt) return;  // uniform per block: barrier-safe
    int lane = threadIdx.x & 63, w = threadIdx.x >> 6;
    int colx = lane & 15, quad = lane >> 4;
    int base = (blockIdx.x * 4 + w) * 16;
    int aidx = base + colx;
    int ua = (aidx < cnt) ? dlist[(size_t)dIdx * N + aidx] : 0;
    int un[4];
    bool uvalid[4];
#pragma unroll
    for (int reg = 0; reg < 4; reg++) {
        int node = base + quad * 4 + reg;
        uvalid[reg] = node < cnt;
        un[reg] = uvalid[reg] ? dlist[(size_t)dIdx * N + node] : 0;
    }

    f32x4 c1[8];
#pragma unroll
    for (int nt = 0; nt < 8; nt++) c1[nt] = (f32x4){0.f, 0.f, 0.f, 0.f};
#pragma unroll
    for (int kt = 0; kt < 8; kt++) {
        f16x8 a;
        if (kt < 4)
            a = cvt8(h + (size_t)ua * 128 + kt * 32 + quad * 8);
        else
            a = *(const f16x8*)(agg + (size_t)ua * 128 + (kt - 4) * 32 + quad * 8);
#pragma unroll
        for (int nt = 0; nt < 8; nt++) {
            f16x8 b = *(const f16x8*)(uw1p + ((size_t)(kt * 8 + nt) * 64 + lane) * 8);
            c1[nt] = MFMA16(a, b, c1[nt]);
        }
    }
#pragma unroll
    for (int nt = 0; nt < 8; nt++) {
        float bias = ub1[nt * 16 + colx];
#pragma unroll
        for (int reg = 0; reg < 4; reg++) {
            int row = quad * 4 + reg;
            lds[w][0][row * 136 + nt * 16 + colx] = (f16)fmaxf(c1[nt][reg] + bias, 0.f);
        }
    }
    __syncthreads();
    f32x4 c2[8];
#pragma unroll
    for (int nt = 0; nt < 8; nt++) c2[nt] = (f32x4){0.f, 0.f, 0.f, 0.f};
#pragma unroll
    for (int kt = 0; kt < 4; kt++) {
        f16x8 a = *(const f16x8*)&lds[w][0][colx * 136 + kt * 32 + quad * 8];
#pragma unroll
        for (int nt = 0; nt < 8; nt++) {
            f16x8 b = *(const f16x8*)(uw2p + ((size_t)(kt * 8 + nt) * 64 + lane) * 8);
            c2[nt] = MFMA16(a, b, c2[nt]);
        }
    }
#pragma unroll
    for (int nt = 0; nt < 8; nt++) {
        float bias = ub2[nt * 16 + colx];
#pragma unroll
        for (int reg = 0; reg < 4; reg++) {
            int row = quad * 4 + reg;
            float v = fmaxf(c2[nt][reg] + bias, 0.f);
            lds[w][1][row * 136 + nt * 16 + colx] = (f16)v;
            if (uvalid[reg]) h[(size_t)un[reg] * 128 + nt * 16 + colx] = v;
        }
    }
    __syncthreads();
    f32x4 c3[8];
#pragma unroll
    for (int nt = 0; nt < 8; nt++) c3[nt] = (f32x4){0.f, 0.f, 0.f, 0.f};
#pragma unroll
    for (int kt = 0; kt < 4; kt++) {
        f16x8 a = *(const f16x8*)&lds[w][1][colx * 136 + kt * 32 + quad * 8];
#pragma unroll
        for (int nt = 0; nt < 8; nt++) {
            f16x8 b = *(const f16x8*)(mw1p + ((size_t)(kt * 8 + nt) * 64 + lane) * 8);
            c3[nt] = MFMA16(a, b, c3[nt]);
        }
    }
#pragma unroll
    for (int nt = 0; nt < 8; nt++) {
        float bias = mb1[nt * 16 + colx];
#pragma unroll
        for (int reg = 0; reg < 4; reg++) {
            if (uvalid[reg])
                t[(size_t)un[reg] * 128 + nt * 16 + colx] = (f16)(c3[nt][reg] + bias);
        }
    }
}

extern "C" void kernel_launch(void* const* d_in, const int* in_sizes, int n_in,
                              void* d_out, int out_size, void* d_ws, size_t ws_size,
                              hipStream_t stream) {
    const float* x    = (const float*)d_in[0];
    const int*   ei   = (const int*)d_in[1];
    const float* eatt = (const float*)d_in[2];
    const int*   dep  = (const int*)d_in[3];
    const float* pw   = (const float*)d_in[4];
    const float* pb   = (const float*)d_in[5];
    const float* mw1  = (const float*)d_in[6];
    const float* mb1  = (const float*)d_in[7];
    const float* mw2  = (const float*)d_in[8];
    const float* mb2  = (const float*)d_in[9];
    const float* uw1  = (const float*)d_in[10];
    const float* ub1  = (const float*)d_in[11];
    const float* uw2  = (const float*)d_in[12];
    const float* ub2  = (const float*)d_in[13];
    float* h = (float*)d_out;

    int N = in_sizes[3];      // depth array
    int E = in_sizes[1] / 2;  // edge_index [2,E]

    char* ws = (char*)d_ws;
    size_t o = 0;
    auto alloc = [&](size_t bytes) -> char* {
        char* p = ws + o;
        o += (bytes + 255) & ~(size_t)255;
        return p;
    };
    f16*   t     = (f16*)alloc((size_t)N * 128 * 2);
    f16*   agg   = (f16*)alloc((size_t)N * 128 * 2);
    int*   degv  = (int*)alloc((size_t)N * 4);
    int*   cur   = (int*)alloc((size_t)N * 4);
    int*   dcnt  = (int*)alloc(64);
    int*   rowp  = (int*)alloc((size_t)(N + 1) * 4);
    int*   esrc  = (int*)alloc((size_t)E * 4);
    float* eso   = (float*)alloc((size_t)E * 4);
    int*   dlist = (int*)alloc((size_t)4 * N * 4);
    f16*   pwp   = (f16*)alloc(128 * 128 * 2);
    f16*   mw1p  = (f16*)alloc(128 * 128 * 2);
    f16*   mw2p  = (f16*)alloc(128 * 128 * 2);
    f16*   uw1p  = (f16*)alloc(256 * 128 * 2);
    f16*   uw2p  = (f16*)alloc(128 * 128 * 2);

    hipMemsetAsync(degv, 0, (size_t)N * 4, stream);
    hipMemsetAsync(cur, 0, (size_t)N * 4, stream);
    hipMemsetAsync(dcnt, 0, 64, stream);

    k_repack<<<8, 256, 0, stream>>>(pw, pwp, 4);
    k_repack<<<8, 256, 0, stream>>>(mw1, mw1p, 4);  // rows 0..127 only
    k_repack<<<8, 256, 0, stream>>>(mw2, mw2p, 4);
    k_repack<<<16, 256, 0, stream>>>(uw1, uw1p, 8);
    k_repack<<<8, 256, 0, stream>>>(uw2, uw2p, 4);

    k_count<<<(E + 255) / 256, 256, 0, stream>>>(ei, E, degv);
    k_nodes<<<(N + 255) / 256, 256, 0, stream>>>(dep, N, dcnt, dlist);
    k_scan<<<1, 1024, 0, stream>>>(degv, rowp, N, E);
    k_scatter<<<(E + 255) / 256, 256, 0, stream>>>(ei, eatt, rowp, cur, esrc, eso, E);
    k_proj<<<(N + 63) / 64, 256, 0, stream>>>(x, pwp, mw1p, pb, mb1, h, t, N);

    for (int d = 1; d <= 4; d++) {
        k_msg<<<(N + 3) / 4, 256, 0, stream>>>(t, mw1, mb2, mw2p, rowp, esrc, eso,
                                               dlist, dcnt, d - 1, agg, N);
        k_upd<<<(N + 63) / 64, 256, 0, stream>>>(h, t, agg, uw1p, uw2p, mw1p, ub1, ub2,
                                                 mb1, dlist, dcnt, d - 1, N);
    }
}

// Round 2
// 555.000 us; speedup vs baseline: 1.3628x; 1.3628x over previous
//
#include <hip/hip_runtime.h>

typedef _Float16 f16;
typedef f16 f16x8 __attribute__((ext_vector_type(8)));
typedef float f32x4 __attribute__((ext_vector_type(4)));

#define MFMA16(a, b, c) __builtin_amdgcn_mfma_f32_16x16x32_f16((a), (b), (c), 0, 0, 0)

static __device__ __forceinline__ f16x8 cvt8(const float* __restrict__ p) {
    f32x4 p0 = *(const f32x4*)p;
    f32x4 p1 = *(const f32x4*)(p + 4);
    f16x8 a;
    a[0] = (f16)p0[0]; a[1] = (f16)p0[1]; a[2] = (f16)p0[2]; a[3] = (f16)p0[3];
    a[4] = (f16)p1[0]; a[5] = (f16)p1[1]; a[6] = (f16)p1[2]; a[7] = (f16)p1[3];
    return a;
}

// Repack all 5 weight matrices ([K x 128] f32) into B-fragment order for
// mfma_f32_16x16x32_f16 in ONE launch. frag (kt,nt): lane holds
// B[kt*32+quad*8+j][nt*16+col]. Blocks: pw 0-7, mw1 8-15, mw2 16-23,
// uw1 24-39 (KT=8), uw2 40-47.
__global__ __launch_bounds__(256) void k_repack_all(
        const float* __restrict__ pw, const float* __restrict__ mw1,
        const float* __restrict__ mw2, const float* __restrict__ uw1,
        const float* __restrict__ uw2,
        f16* __restrict__ pwp, f16* __restrict__ mw1p, f16* __restrict__ mw2p,
        f16* __restrict__ uw1p, f16* __restrict__ uw2p) {
    int b = blockIdx.x;
    const float* W; f16* out; int fb;
    if (b < 8)       { W = pw;  out = pwp;  fb = b; }
    else if (b < 16) { W = mw1; out = mw1p; fb = b - 8; }
    else if (b < 24) { W = mw2; out = mw2p; fb = b - 16; }
    else if (b < 40) { W = uw1; out = uw1p; fb = b - 24; }
    else             { W = uw2; out = uw2p; fb = b - 40; }
    int idx = fb * 256 + threadIdx.x;
    int lane = idx & 63;
    int frag = idx >> 6;
    int nt = frag & 7;
    int kt = frag >> 3;
    int colx = lane & 15, quad = lane >> 4;
    f16* o = out + (size_t)idx * 8;
    const float* wb = W + (size_t)(kt * 32 + quad * 8) * 128 + nt * 16 + colx;
#pragma unroll
    for (int j = 0; j < 8; j++) o[j] = (f16)wb[(size_t)j * 128];
}

__global__ __launch_bounds__(256) void k_count(const int* __restrict__ ei, int E,
                                               int* __restrict__ degv) {
    int e = blockIdx.x * blockDim.x + threadIdx.x;
    if (e < E) atomicAdd(&degv[ei[E + e]], 1);
}

// Depth classification WITHOUT contended global atomics: LDS histogram (4
// buckets), one global atomicAdd per bucket per block, block-local ranks.
__global__ __launch_bounds__(256) void k_nodes(const int* __restrict__ dep, int N,
                                               int* __restrict__ dcnt, int* __restrict__ dlist) {
    __shared__ int lcnt[4];
    __shared__ int lbase[4];
    int t = threadIdx.x;
    if (t < 4) lcnt[t] = 0;
    __syncthreads();
    int v = blockIdx.x * 256 + t;
    int d = (v < N) ? dep[v] : 0;
    int p = -1;
    if (d >= 1 && d <= 4) p = atomicAdd(&lcnt[d - 1], 1);
    __syncthreads();
    if (t < 4) lbase[t] = (lcnt[t] > 0) ? atomicAdd(&dcnt[t], lcnt[t]) : 0;
    __syncthreads();
    if (d >= 1 && d <= 4) dlist[(size_t)(d - 1) * N + lbase[d - 1] + p] = v;
}

__global__ __launch_bounds__(1024) void k_scan(const int* __restrict__ degv,
                                               int* __restrict__ rowp, int N, int E) {
    __shared__ int lds[1024];
    int t = threadIdx.x;
    int chunk = (N + 1023) >> 10;
    int s0 = t * chunk;
    int s1 = s0 + chunk; if (s1 > N) s1 = N;
    int s = 0;
    for (int i = s0; i < s1; i++) s += degv[i];
    lds[t] = s;
    __syncthreads();
    for (int d = 1; d < 1024; d <<= 1) {
        int v = (t >= d) ? lds[t - d] : 0;
        __syncthreads();
        lds[t] += v;
        __syncthreads();
    }
    int off = (t == 0) ? 0 : lds[t - 1];
    for (int i = s0; i < s1; i++) { rowp[i] = off; off += degv[i]; }
    if (t == 0) rowp[N] = E;
}

__global__ __launch_bounds__(256) void k_scatter(const int* __restrict__ ei,
                                                 const float* __restrict__ eattr,
                                                 const int* __restrict__ rowp,
                                                 int* __restrict__ cur,
                                                 int* __restrict__ esrc,
                                                 float* __restrict__ eso, int E) {
    int e = blockIdx.x * blockDim.x + threadIdx.x;
    if (e >= E) return;
    int s = ei[e], d = ei[E + e];
    int p = rowp[d] + atomicAdd(&cur[d], 1);
    esrc[p] = s;
    eso[p] = eattr[e];
}

// h = x @ pw + pb ;  t = h @ mw1[0:128] + mb1   (one wave = 16 node rows).
// LDS slices are wave-private: no block barrier needed (same-wave
// ds_write->ds_read ordering is enforced by compiler lgkmcnt).
__global__ __launch_bounds__(256) void k_proj(const float* __restrict__ x,
                                              const f16* __restrict__ pwp,
                                              const f16* __restrict__ mw1p,
                                              const float* __restrict__ pb,
                                              const float* __restrict__ mb1,
                                              float* __restrict__ h,
                                              f16* __restrict__ t, int N) {
    __shared__ __align__(16) f16 lds[4][16 * 136];
    int lane = threadIdx.x & 63, w = threadIdx.x >> 6;
    int colx = lane & 15, quad = lane >> 4;
    int base = (blockIdx.x * 4 + w) * 16;
    int arow = base + colx;
    int u = arow < N ? arow : N - 1;

    f32x4 c1[8];
#pragma unroll
    for (int nt = 0; nt < 8; nt++) c1[nt] = (f32x4){0.f, 0.f, 0.f, 0.f};
#pragma unroll
    for (int kt = 0; kt < 4; kt++) {
        f16x8 a = cvt8(x + (size_t)u * 128 + kt * 32 + quad * 8);
#pragma unroll
        for (int nt = 0; nt < 8; nt++) {
            f16x8 b = *(const f16x8*)(pwp + ((size_t)(kt * 8 + nt) * 64 + lane) * 8);
            c1[nt] = MFMA16(a, b, c1[nt]);
        }
    }
#pragma unroll
    for (int nt = 0; nt < 8; nt++) {
        float bias = pb[nt * 16 + colx];
#pragma unroll
        for (int reg = 0; reg < 4; reg++) {
            int row = quad * 4 + reg;
            int node = base + row;
            float v = c1[nt][reg] + bias;
            lds[w][row * 136 + nt * 16 + colx] = (f16)v;
            if (node < N) h[(size_t)node * 128 + nt * 16 + colx] = v;
        }
    }
    f32x4 c2[8];
#pragma unroll
    for (int nt = 0; nt < 8; nt++) c2[nt] = (f32x4){0.f, 0.f, 0.f, 0.f};
#pragma unroll
    for (int kt = 0; kt < 4; kt++) {
        f16x8 a = *(const f16x8*)&lds[w][colx * 136 + kt * 32 + quad * 8];
#pragma unroll
        for (int nt = 0; nt < 8; nt++) {
            f16x8 b = *(const f16x8*)(mw1p + ((size_t)(kt * 8 + nt) * 64 + lane) * 8);
            c2[nt] = MFMA16(a, b, c2[nt]);
        }
    }
#pragma unroll
    for (int nt = 0; nt < 8; nt++) {
        float bias = mb1[nt * 16 + colx];
#pragma unroll
        for (int reg = 0; reg < 4; reg++) {
            int node = base + quad * 4 + reg;
            if (node < N) t[(size_t)node * 128 + nt * 16 + colx] = (f16)(c2[nt][reg] + bias);
        }
    }
}

// Persistent: waves stride over this depth's dst nodes. Per node: build
// hidden A-tiles (16 edges), msg = relu(hidden @ mw2 + mb2), masked
// row-reduce into agg, mean-divide.
__global__ __launch_bounds__(256) void k_msg(const f16* __restrict__ t,
                                             const float* __restrict__ mw1,
                                             const float* __restrict__ mb2,
                                             const f16* __restrict__ mw2p,
                                             const int* __restrict__ rowp,
                                             const int* __restrict__ esrc,
                                             const float* __restrict__ eso,
                                             const int* __restrict__ dlist,
                                             const int* __restrict__ dcnt, int dIdx,
                                             f16* __restrict__ agg, int N) {
    int lane = threadIdx.x & 63;
    int gw = blockIdx.x * 4 + (threadIdx.x >> 6);
    int nw = gridDim.x * 4;
    int cnt = dcnt[dIdx];
    int colx = lane & 15, quad = lane >> 4;

    const float* w1r = mw1 + 128 * 128;  // row 128 of mw1: edge-attr weights
    float w1f[4][8];
#pragma unroll
    for (int kt = 0; kt < 4; kt++) {
        f32x4 q0 = *(const f32x4*)(w1r + kt * 32 + quad * 8);
        f32x4 q1 = *(const f32x4*)(w1r + kt * 32 + quad * 8 + 4);
        w1f[kt][0] = q0[0]; w1f[kt][1] = q0[1]; w1f[kt][2] = q0[2]; w1f[kt][3] = q0[3];
        w1f[kt][4] = q1[0]; w1f[kt][5] = q1[1]; w1f[kt][6] = q1[2]; w1f[kt][7] = q1[3];
    }
    float mb2v[8];
#pragma unroll
    for (int nt = 0; nt < 8; nt++) mb2v[nt] = mb2[nt * 16 + colx];

    for (int wid = gw; wid < cnt; wid += nw) {
        int u = dlist[(size_t)dIdx * N + wid];
        int e0 = rowp[u], e1 = rowp[u + 1];
        float aggv[8] = {0.f, 0.f, 0.f, 0.f, 0.f, 0.f, 0.f, 0.f};

        for (int bs = e0; bs < e1; bs += 16) {
            int es = bs + colx;
            if (es >= e1) es = e0;  // safe dummy; masked in reduction
            int src = esrc[es];
            float ea = eso[es];
            const f16* trow = t + (size_t)src * 128;
            f16x8 afr[4];
#pragma unroll
            for (int kt = 0; kt < 4; kt++) {
                f16x8 tv = *(const f16x8*)(trow + kt * 32 + quad * 8);
                f16x8 hv;
#pragma unroll
                for (int j = 0; j < 8; j++) {
                    float v = (float)tv[j] + ea * w1f[kt][j];
                    hv[j] = (f16)fmaxf(v, 0.f);
                }
                afr[kt] = hv;
            }
#pragma unroll
            for (int nt = 0; nt < 8; nt++) {
                f32x4 c = (f32x4){0.f, 0.f, 0.f, 0.f};
#pragma unroll
                for (int kt = 0; kt < 4; kt++) {
                    f16x8 b = *(const f16x8*)(mw2p + ((size_t)(kt * 8 + nt) * 64 + lane) * 8);
                    c = MFMA16(afr[kt], b, c);
                }
                float s = 0.f;
#pragma unroll
                for (int reg = 0; reg < 4; reg++) {
                    if (bs + quad * 4 + reg < e1) s += fmaxf(c[reg] + mb2v[nt], 0.f);
                }
                aggv[nt] += s;
            }
        }
        int deg = e1 - e0;
        float inv = 1.f / (float)(deg > 1 ? deg : 1);
#pragma unroll
        for (int nt = 0; nt < 8; nt++) {
            float s = aggv[nt];
            s += __shfl_xor(s, 16, 64);
            s += __shfl_xor(s, 32, 64);
            if (quad == 0) agg[(size_t)u * 128 + nt * 16 + colx] = (f16)(s * inv);
        }
    }
}

// Persistent: waves stride over 16-node tiles of this depth.
// h_new = relu(relu([h,agg]@uw1+ub1)@uw2+ub2); write h (f32), refresh
// t = h_new @ mw1 + mb1. LDS wave-private, no barriers.
__global__ __launch_bounds__(256) void k_upd(float* __restrict__ h, f16* __restrict__ t,
                                             const f16* __restrict__ agg,
                                             const f16* __restrict__ uw1p,
                                             const f16* __restrict__ uw2p,
                                             const f16* __restrict__ mw1p,
                                             const float* __restrict__ ub1,
                                             const float* __restrict__ ub2,
                                             const float* __restrict__ mb1,
                                             const int* __restrict__ dlist,
                                             const int* __restrict__ dcnt, int dIdx, int N) {
    __shared__ __align__(16) f16 lds[4][2][16 * 136];
    int cnt = dcnt[dIdx];
    int lane = threadIdx.x & 63, w = threadIdx.x >> 6;
    int colx = lane & 15, quad = lane >> 4;
    int gw = blockIdx.x * 4 + w;
    int nw = gridDim.x * 4;
    int ntiles = (cnt + 15) >> 4;

    for (int tb = gw; tb < ntiles; tb += nw) {
        int base = tb * 16;
        int aidx = base + colx;
        int ua = (aidx < cnt) ? dlist[(size_t)dIdx * N + aidx] : 0;
        int un[4];
        bool uvalid[4];
#pragma unroll
        for (int reg = 0; reg < 4; reg++) {
            int node = base + quad * 4 + reg;
            uvalid[reg] = node < cnt;
            un[reg] = uvalid[reg] ? dlist[(size_t)dIdx * N + node] : 0;
        }

        f32x4 c1[8];
#pragma unroll
        for (int nt = 0; nt < 8; nt++) c1[nt] = (f32x4){0.f, 0.f, 0.f, 0.f};
#pragma unroll
        for (int kt = 0; kt < 8; kt++) {
            f16x8 a;
            if (kt < 4)
                a = cvt8(h + (size_t)ua * 128 + kt * 32 + quad * 8);
            else
                a = *(const f16x8*)(agg + (size_t)ua * 128 + (kt - 4) * 32 + quad * 8);
#pragma unroll
            for (int nt = 0; nt < 8; nt++) {
                f16x8 b = *(const f16x8*)(uw1p + ((size_t)(kt * 8 + nt) * 64 + lane) * 8);
                c1[nt] = MFMA16(a, b, c1[nt]);
            }
        }
#pragma unroll
        for (int nt = 0; nt < 8; nt++) {
            float bias = ub1[nt * 16 + colx];
#pragma unroll
            for (int reg = 0; reg < 4; reg++) {
                int row = quad * 4 + reg;
                lds[w][0][row * 136 + nt * 16 + colx] = (f16)fmaxf(c1[nt][reg] + bias, 0.f);
            }
        }
        f32x4 c2[8];
#pragma unroll
        for (int nt = 0; nt < 8; nt++) c2[nt] = (f32x4){0.f, 0.f, 0.f, 0.f};
#pragma unroll
        for (int kt = 0; kt < 4; kt++) {
            f16x8 a = *(const f16x8*)&lds[w][0][colx * 136 + kt * 32 + quad * 8];
#pragma unroll
            for (int nt = 0; nt < 8; nt++) {
                f16x8 b = *(const f16x8*)(uw2p + ((size_t)(kt * 8 + nt) * 64 + lane) * 8);
                c2[nt] = MFMA16(a, b, c2[nt]);
            }
        }
#pragma unroll
        for (int nt = 0; nt < 8; nt++) {
            float bias = ub2[nt * 16 + colx];
#pragma unroll
            for (int reg = 0; reg < 4; reg++) {
                int row = quad * 4 + reg;
                float v = fmaxf(c2[nt][reg] + bias, 0.f);
                lds[w][1][row * 136 + nt * 16 + colx] = (f16)v;
                if (uvalid[reg]) h[(size_t)un[reg] * 128 + nt * 16 + colx] = v;
            }
        }
        f32x4 c3[8];
#pragma unroll
        for (int nt = 0; nt < 8; nt++) c3[nt] = (f32x4){0.f, 0.f, 0.f, 0.f};
#pragma unroll
        for (int kt = 0; kt < 4; kt++) {
            f16x8 a = *(const f16x8*)&lds[w][1][colx * 136 + kt * 32 + quad * 8];
#pragma unroll
            for (int nt = 0; nt < 8; nt++) {
                f16x8 b = *(const f16x8*)(mw1p + ((size_t)(kt * 8 + nt) * 64 + lane) * 8);
                c3[nt] = MFMA16(a, b, c3[nt]);
            }
        }
#pragma unroll
        for (int nt = 0; nt < 8; nt++) {
            float bias = mb1[nt * 16 + colx];
#pragma unroll
            for (int reg = 0; reg < 4; reg++) {
                if (uvalid[reg])
                    t[(size_t)un[reg] * 128 + nt * 16 + colx] = (f16)(c3[nt][reg] + bias);
            }
        }
    }
}

extern "C" void kernel_launch(void* const* d_in, const int* in_sizes, int n_in,
                              void* d_out, int out_size, void* d_ws, size_t ws_size,
                              hipStream_t stream) {
    const float* x    = (const float*)d_in[0];
    const int*   ei   = (const int*)d_in[1];
    const float* eatt = (const float*)d_in[2];
    const int*   dep  = (const int*)d_in[3];
    const float* pw   = (const float*)d_in[4];
    const float* pb   = (const float*)d_in[5];
    const float* mw1  = (const float*)d_in[6];
    const float* mb1  = (const float*)d_in[7];
    const float* mw2  = (const float*)d_in[8];
    const float* mb2  = (const float*)d_in[9];
    const float* uw1  = (const float*)d_in[10];
    const float* ub1  = (const float*)d_in[11];
    const float* uw2  = (const float*)d_in[12];
    const float* ub2  = (const float*)d_in[13];
    float* h = (float*)d_out;

    int N = in_sizes[3];      // depth array
    int E = in_sizes[1] / 2;  // edge_index [2,E]

    char* ws = (char*)d_ws;
    size_t o = 0;
    auto alloc = [&](size_t bytes) -> char* {
        char* p = ws + o;
        o += (bytes + 255) & ~(size_t)255;
        return p;
    };
    f16*   t     = (f16*)alloc((size_t)N * 128 * 2);
    f16*   agg   = (f16*)alloc((size_t)N * 128 * 2);
    // degv, cur, dcnt contiguous -> one memset
    char*  z0    = (char*)alloc(0);
    int*   degv  = (int*)alloc((size_t)N * 4);
    int*   cur   = (int*)alloc((size_t)N * 4);
    int*   dcnt  = (int*)alloc(64);
    size_t zbytes = (size_t)((char*)alloc(0) - z0);
    int*   rowp  = (int*)alloc((size_t)(N + 1) * 4);
    int*   esrc  = (int*)alloc((size_t)E * 4);
    float* eso   = (float*)alloc((size_t)E * 4);
    int*   dlist = (int*)alloc((size_t)4 * N * 4);
    f16*   pwp   = (f16*)alloc(128 * 128 * 2);
    f16*   mw1p  = (f16*)alloc(128 * 128 * 2);
    f16*   mw2p  = (f16*)alloc(128 * 128 * 2);
    f16*   uw1p  = (f16*)alloc(256 * 128 * 2);
    f16*   uw2p  = (f16*)alloc(128 * 128 * 2);

    hipMemsetAsync(z0, 0, zbytes, stream);

    k_repack_all<<<48, 256, 0, stream>>>(pw, mw1, mw2, uw1, uw2,
                                         pwp, mw1p, mw2p, uw1p, uw2p);
    k_count<<<(E + 255) / 256, 256, 0, stream>>>(ei, E, degv);
    k_nodes<<<(N + 255) / 256, 256, 0, stream>>>(dep, N, dcnt, dlist);
    k_scan<<<1, 1024, 0, stream>>>(degv, rowp, N, E);
    k_scatter<<<(E + 255) / 256, 256, 0, stream>>>(ei, eatt, rowp, cur, esrc, eso, E);
    k_proj<<<(N + 63) / 64, 256, 0, stream>>>(x, pwp, mw1p, pb, mb1, h, t, N);

    for (int d = 1; d <= 4; d++) {
        k_msg<<<640, 256, 0, stream>>>(t, mw1, mb2, mw2p, rowp, esrc, eso,
                                       dlist, dcnt, d - 1, agg, N);
        k_upd<<<256, 256, 0, stream>>>(h, t, agg, uw1p, uw2p, mw1p, ub1, ub2,
                                       mb1, dlist, dcnt, d - 1, N);
    }
}

// Round 3
// 463.010 us; speedup vs baseline: 1.6335x; 1.1987x over previous
//
#include <hip/hip_runtime.h>

typedef _Float16 f16;
typedef f16 f16x8 __attribute__((ext_vector_type(8)));
typedef float f32x4 __attribute__((ext_vector_type(4)));

#define MFMA16(a, b, c) __builtin_amdgcn_mfma_f32_16x16x32_f16((a), (b), (c), 0, 0, 0)

static __device__ __forceinline__ f16x8 cvt8(const float* __restrict__ p) {
    f32x4 p0 = *(const f32x4*)p;
    f32x4 p1 = *(const f32x4*)(p + 4);
    f16x8 a;
    a[0] = (f16)p0[0]; a[1] = (f16)p0[1]; a[2] = (f16)p0[2]; a[3] = (f16)p0[3];
    a[4] = (f16)p1[0]; a[5] = (f16)p1[1]; a[6] = (f16)p1[2]; a[7] = (f16)p1[3];
    return a;
}

// Fused prep: blocks [0,48) repack 5 weight mats into B-fragment order;
// blocks [48, 48+CB) count in-degrees; blocks [48+CB, ...) classify nodes
// by depth (LDS histogram, 4 global atomics per block).
__global__ __launch_bounds__(256) void k_prep(
        const float* __restrict__ pw, const float* __restrict__ mw1,
        const float* __restrict__ mw2, const float* __restrict__ uw1,
        const float* __restrict__ uw2,
        f16* __restrict__ pwp, f16* __restrict__ mw1p, f16* __restrict__ mw2p,
        f16* __restrict__ uw1p, f16* __restrict__ uw2p,
        const int* __restrict__ ei, int* __restrict__ degv,
        const int* __restrict__ dep, int* __restrict__ dcnt,
        int* __restrict__ dlist, int CB, int E, int N) {
    __shared__ int lcnt[4];
    __shared__ int lbase[4];
    int b = blockIdx.x;
    int t = threadIdx.x;
    if (b < 48) {
        // ---- repack ----
        const float* W; f16* out; int fb;
        if (b < 8)       { W = pw;  out = pwp;  fb = b; }
        else if (b < 16) { W = mw1; out = mw1p; fb = b - 8; }
        else if (b < 24) { W = mw2; out = mw2p; fb = b - 16; }
        else if (b < 40) { W = uw1; out = uw1p; fb = b - 24; }
        else             { W = uw2; out = uw2p; fb = b - 40; }
        int idx = fb * 256 + t;
        int lane = idx & 63;
        int frag = idx >> 6;
        int nt = frag & 7;
        int kt = frag >> 3;
        int colx = lane & 15, quad = lane >> 4;
        f16* o = out + (size_t)idx * 8;
        const float* wb = W + (size_t)(kt * 32 + quad * 8) * 128 + nt * 16 + colx;
#pragma unroll
        for (int j = 0; j < 8; j++) o[j] = (f16)wb[(size_t)j * 128];
    } else if (b < 48 + CB) {
        // ---- degree count ----
        int e = (b - 48) * 256 + t;
        if (e < E) atomicAdd(&degv[ei[E + e]], 1);
    } else {
        // ---- depth classification ----
        if (t < 4) lcnt[t] = 0;
        __syncthreads();
        int v = (b - 48 - CB) * 256 + t;
        int d = (v < N) ? dep[v] : 0;
        int p = -1;
        if (d >= 1 && d <= 4) p = atomicAdd(&lcnt[d - 1], 1);
        __syncthreads();
        if (t < 4) lbase[t] = (lcnt[t] > 0) ? atomicAdd(&dcnt[t], lcnt[t]) : 0;
        __syncthreads();
        if (d >= 1 && d <= 4) dlist[(size_t)(d - 1) * N + lbase[d - 1] + p] = v;
    }
}

// Fused: blocks [0,SB) = scan stage A (per-block reduce of degv -> bsum);
// blocks [SB,...) = proj: h = x@pw+pb; t = h@mw1[0:128]+mb1 (wave-private LDS).
__global__ __launch_bounds__(256) void k_mid(
        const int* __restrict__ degv, int* __restrict__ bsum, int SB,
        const float* __restrict__ x, const f16* __restrict__ pwp,
        const f16* __restrict__ mw1p, const float* __restrict__ pb,
        const float* __restrict__ mb1, float* __restrict__ h,
        f16* __restrict__ t, int N) {
    __shared__ __align__(16) f16 lds[4][16 * 136];
    __shared__ int wsum[4];
    int t0 = threadIdx.x;
    if ((int)blockIdx.x < SB) {
        // ---- scan stage A ----
        int idx = blockIdx.x * 256 + t0;
        int v = (idx < N) ? degv[idx] : 0;
#pragma unroll
        for (int off = 32; off; off >>= 1) v += __shfl_down(v, off, 64);
        if ((t0 & 63) == 0) wsum[t0 >> 6] = v;
        __syncthreads();
        if (t0 == 0) bsum[blockIdx.x] = wsum[0] + wsum[1] + wsum[2] + wsum[3];
        return;
    }
    // ---- proj ----
    int lane = t0 & 63, w = t0 >> 6;
    int colx = lane & 15, quad = lane >> 4;
    int base = ((blockIdx.x - SB) * 4 + w) * 16;
    int arow = base + colx;
    int u = arow < N ? arow : N - 1;

    f32x4 c1[8];
#pragma unroll
    for (int nt = 0; nt < 8; nt++) c1[nt] = (f32x4){0.f, 0.f, 0.f, 0.f};
#pragma unroll
    for (int kt = 0; kt < 4; kt++) {
        f16x8 a = cvt8(x + (size_t)u * 128 + kt * 32 + quad * 8);
#pragma unroll
        for (int nt = 0; nt < 8; nt++) {
            f16x8 b = *(const f16x8*)(pwp + ((size_t)(kt * 8 + nt) * 64 + lane) * 8);
            c1[nt] = MFMA16(a, b, c1[nt]);
        }
    }
#pragma unroll
    for (int nt = 0; nt < 8; nt++) {
        float bias = pb[nt * 16 + colx];
#pragma unroll
        for (int reg = 0; reg < 4; reg++) {
            int row = quad * 4 + reg;
            int node = base + row;
            float v = c1[nt][reg] + bias;
            lds[w][row * 136 + nt * 16 + colx] = (f16)v;
            if (node < N) h[(size_t)node * 128 + nt * 16 + colx] = v;
        }
    }
    f32x4 c2[8];
#pragma unroll
    for (int nt = 0; nt < 8; nt++) c2[nt] = (f32x4){0.f, 0.f, 0.f, 0.f};
#pragma unroll
    for (int kt = 0; kt < 4; kt++) {
        f16x8 a = *(const f16x8*)&lds[w][colx * 136 + kt * 32 + quad * 8];
#pragma unroll
        for (int nt = 0; nt < 8; nt++) {
            f16x8 b = *(const f16x8*)(mw1p + ((size_t)(kt * 8 + nt) * 64 + lane) * 8);
            c2[nt] = MFMA16(a, b, c2[nt]);
        }
    }
#pragma unroll
    for (int nt = 0; nt < 8; nt++) {
        float bias = mb1[nt * 16 + colx];
#pragma unroll
        for (int reg = 0; reg < 4; reg++) {
            int node = base + quad * 4 + reg;
            if (node < N) t[(size_t)node * 128 + nt * 16 + colx] = (f16)(c2[nt][reg] + bias);
        }
    }
}

// Scan stage C: block b sums bsum[0..b-1], block-local inclusive scan of its
// degv chunk, writes exclusive prefix to rowp.
__global__ __launch_bounds__(256) void k_scanC(const int* __restrict__ degv,
                                               const int* __restrict__ bsum,
                                               int* __restrict__ rowp, int N, int E) {
    __shared__ int lds[256];
    __shared__ int wo[4];
    int b = blockIdx.x, t = threadIdx.x;
    int idx = b * 256 + t;
    int v = (idx < N) ? degv[idx] : 0;
    lds[t] = v;
    __syncthreads();
#pragma unroll
    for (int d = 1; d < 256; d <<= 1) {
        int u = (t >= d) ? lds[t - d] : 0;
        __syncthreads();
        lds[t] += u;
        __syncthreads();
    }
    int off = 0;
    for (int j = t; j < b; j += 256) off += bsum[j];
#pragma unroll
    for (int o = 32; o; o >>= 1) off += __shfl_down(off, o, 64);
    if ((t & 63) == 0) wo[t >> 6] = off;
    __syncthreads();
    int boff = wo[0] + wo[1] + wo[2] + wo[3];
    if (idx < N) rowp[idx] = boff + lds[t] - v;
    if (b == 0 && t == 0) rowp[N] = E;
}

__global__ __launch_bounds__(256) void k_scatter(const int* __restrict__ ei,
                                                 const float* __restrict__ eattr,
                                                 const int* __restrict__ rowp,
                                                 int* __restrict__ cur,
                                                 int* __restrict__ esrc,
                                                 float* __restrict__ eso, int E) {
    int e = blockIdx.x * blockDim.x + threadIdx.x;
    if (e >= E) return;
    int s = ei[e], d = ei[E + e];
    int p = rowp[d] + atomicAdd(&cur[d], 1);
    esrc[p] = s;
    eso[p] = eattr[e];
}

// Persistent: waves stride over this depth's dst nodes. Per node: build
// hidden A-tiles (16 edges), msg = relu(hidden @ mw2 + mb2), masked
// row-reduce into agg, mean-divide.
__global__ __launch_bounds__(256) void k_msg(const f16* __restrict__ t,
                                             const float* __restrict__ mw1,
                                             const float* __restrict__ mb2,
                                             const f16* __restrict__ mw2p,
                                             const int* __restrict__ rowp,
                                             const int* __restrict__ esrc,
                                             const float* __restrict__ eso,
                                             const int* __restrict__ dlist,
                                             const int* __restrict__ dcnt, int dIdx,
                                             f16* __restrict__ agg, int N) {
    int lane = threadIdx.x & 63;
    int gw = blockIdx.x * 4 + (threadIdx.x >> 6);
    int nw = gridDim.x * 4;
    int cnt = dcnt[dIdx];
    int colx = lane & 15, quad = lane >> 4;

    const float* w1r = mw1 + 128 * 128;  // row 128 of mw1: edge-attr weights
    float w1f[4][8];
#pragma unroll
    for (int kt = 0; kt < 4; kt++) {
        f32x4 q0 = *(const f32x4*)(w1r + kt * 32 + quad * 8);
        f32x4 q1 = *(const f32x4*)(w1r + kt * 32 + quad * 8 + 4);
        w1f[kt][0] = q0[0]; w1f[kt][1] = q0[1]; w1f[kt][2] = q0[2]; w1f[kt][3] = q0[3];
        w1f[kt][4] = q1[0]; w1f[kt][5] = q1[1]; w1f[kt][6] = q1[2]; w1f[kt][7] = q1[3];
    }
    float mb2v[8];
#pragma unroll
    for (int nt = 0; nt < 8; nt++) mb2v[nt] = mb2[nt * 16 + colx];

    for (int wid = gw; wid < cnt; wid += nw) {
        int u = dlist[(size_t)dIdx * N + wid];
        int e0 = rowp[u], e1 = rowp[u + 1];
        float aggv[8] = {0.f, 0.f, 0.f, 0.f, 0.f, 0.f, 0.f, 0.f};

        for (int bs = e0; bs < e1; bs += 16) {
            int es = bs + colx;
            if (es >= e1) es = e0;  // safe dummy; masked in reduction
            int src = esrc[es];
            float ea = eso[es];
            const f16* trow = t + (size_t)src * 128;
            f16x8 afr[4];
#pragma unroll
            for (int kt = 0; kt < 4; kt++) {
                f16x8 tv = *(const f16x8*)(trow + kt * 32 + quad * 8);
                f16x8 hv;
#pragma unroll
                for (int j = 0; j < 8; j++) {
                    float v = (float)tv[j] + ea * w1f[kt][j];
                    hv[j] = (f16)fmaxf(v, 0.f);
                }
                afr[kt] = hv;
            }
#pragma unroll
            for (int nt = 0; nt < 8; nt++) {
                f32x4 c = (f32x4){0.f, 0.f, 0.f, 0.f};
#pragma unroll
                for (int kt = 0; kt < 4; kt++) {
                    f16x8 b = *(const f16x8*)(mw2p + ((size_t)(kt * 8 + nt) * 64 + lane) * 8);
                    c = MFMA16(afr[kt], b, c);
                }
                float s = 0.f;
#pragma unroll
                for (int reg = 0; reg < 4; reg++) {
                    if (bs + quad * 4 + reg < e1) s += fmaxf(c[reg] + mb2v[nt], 0.f);
                }
                aggv[nt] += s;
            }
        }
        int deg = e1 - e0;
        float inv = 1.f / (float)(deg > 1 ? deg : 1);
#pragma unroll
        for (int nt = 0; nt < 8; nt++) {
            float s = aggv[nt];
            s += __shfl_xor(s, 16, 64);
            s += __shfl_xor(s, 32, 64);
            if (quad == 0) agg[(size_t)u * 128 + nt * 16 + colx] = (f16)(s * inv);
        }
    }
}

// Persistent: waves stride over 16-node tiles of this depth.
// h_new = relu(relu([h,agg]@uw1+ub1)@uw2+ub2); write h (f32), refresh
// t = h_new @ mw1 + mb1. LDS wave-private, no barriers.
__global__ __launch_bounds__(256) void k_upd(float* __restrict__ h, f16* __restrict__ t,
                                             const f16* __restrict__ agg,
                                             const f16* __restrict__ uw1p,
                                             const f16* __restrict__ uw2p,
                                             const f16* __restrict__ mw1p,
                                             const float* __restrict__ ub1,
                                             const float* __restrict__ ub2,
                                             const float* __restrict__ mb1,
                                             const int* __restrict__ dlist,
                                             const int* __restrict__ dcnt, int dIdx, int N) {
    __shared__ __align__(16) f16 lds[4][2][16 * 136];
    int cnt = dcnt[dIdx];
    int lane = threadIdx.x & 63, w = threadIdx.x >> 6;
    int colx = lane & 15, quad = lane >> 4;
    int gw = blockIdx.x * 4 + w;
    int nw = gridDim.x * 4;
    int ntiles = (cnt + 15) >> 4;

    for (int tb = gw; tb < ntiles; tb += nw) {
        int base = tb * 16;
        int aidx = base + colx;
        int ua = (aidx < cnt) ? dlist[(size_t)dIdx * N + aidx] : 0;
        int un[4];
        bool uvalid[4];
#pragma unroll
        for (int reg = 0; reg < 4; reg++) {
            int node = base + quad * 4 + reg;
            uvalid[reg] = node < cnt;
            un[reg] = uvalid[reg] ? dlist[(size_t)dIdx * N + node] : 0;
        }

        f32x4 c1[8];
#pragma unroll
        for (int nt = 0; nt < 8; nt++) c1[nt] = (f32x4){0.f, 0.f, 0.f, 0.f};
#pragma unroll
        for (int kt = 0; kt < 8; kt++) {
            f16x8 a;
            if (kt < 4)
                a = cvt8(h + (size_t)ua * 128 + kt * 32 + quad * 8);
            else
                a = *(const f16x8*)(agg + (size_t)ua * 128 + (kt - 4) * 32 + quad * 8);
#pragma unroll
            for (int nt = 0; nt < 8; nt++) {
                f16x8 b = *(const f16x8*)(uw1p + ((size_t)(kt * 8 + nt) * 64 + lane) * 8);
                c1[nt] = MFMA16(a, b, c1[nt]);
            }
        }
#pragma unroll
        for (int nt = 0; nt < 8; nt++) {
            float bias = ub1[nt * 16 + colx];
#pragma unroll
            for (int reg = 0; reg < 4; reg++) {
                int row = quad * 4 + reg;
                lds[w][0][row * 136 + nt * 16 + colx] = (f16)fmaxf(c1[nt][reg] + bias, 0.f);
            }
        }
        f32x4 c2[8];
#pragma unroll
        for (int nt = 0; nt < 8; nt++) c2[nt] = (f32x4){0.f, 0.f, 0.f, 0.f};
#pragma unroll
        for (int kt = 0; kt < 4; kt++) {
            f16x8 a = *(const f16x8*)&lds[w][0][colx * 136 + kt * 32 + quad * 8];
#pragma unroll
            for (int nt = 0; nt < 8; nt++) {
                f16x8 b = *(const f16x8*)(uw2p + ((size_t)(kt * 8 + nt) * 64 + lane) * 8);
                c2[nt] = MFMA16(a, b, c2[nt]);
            }
        }
#pragma unroll
        for (int nt = 0; nt < 8; nt++) {
            float bias = ub2[nt * 16 + colx];
#pragma unroll
            for (int reg = 0; reg < 4; reg++) {
                int row = quad * 4 + reg;
                float v = fmaxf(c2[nt][reg] + bias, 0.f);
                lds[w][1][row * 136 + nt * 16 + colx] = (f16)v;
                if (uvalid[reg]) h[(size_t)un[reg] * 128 + nt * 16 + colx] = v;
            }
        }
        f32x4 c3[8];
#pragma unroll
        for (int nt = 0; nt < 8; nt++) c3[nt] = (f32x4){0.f, 0.f, 0.f, 0.f};
#pragma unroll
        for (int kt = 0; kt < 4; kt++) {
            f16x8 a = *(const f16x8*)&lds[w][1][colx * 136 + kt * 32 + quad * 8];
#pragma unroll
            for (int nt = 0; nt < 8; nt++) {
                f16x8 b = *(const f16x8*)(mw1p + ((size_t)(kt * 8 + nt) * 64 + lane) * 8);
                c3[nt] = MFMA16(a, b, c3[nt]);
            }
        }
#pragma unroll
        for (int nt = 0; nt < 8; nt++) {
            float bias = mb1[nt * 16 + colx];
#pragma unroll
            for (int reg = 0; reg < 4; reg++) {
                if (uvalid[reg])
                    t[(size_t)un[reg] * 128 + nt * 16 + colx] = (f16)(c3[nt][reg] + bias);
            }
        }
    }
}

extern "C" void kernel_launch(void* const* d_in, const int* in_sizes, int n_in,
                              void* d_out, int out_size, void* d_ws, size_t ws_size,
                              hipStream_t stream) {
    const float* x    = (const float*)d_in[0];
    const int*   ei   = (const int*)d_in[1];
    const float* eatt = (const float*)d_in[2];
    const int*   dep  = (const int*)d_in[3];
    const float* pw   = (const float*)d_in[4];
    const float* pb   = (const float*)d_in[5];
    const float* mw1  = (const float*)d_in[6];
    const float* mb1  = (const float*)d_in[7];
    const float* mw2  = (const float*)d_in[8];
    const float* mb2  = (const float*)d_in[9];
    const float* uw1  = (const float*)d_in[10];
    const float* ub1  = (const float*)d_in[11];
    const float* uw2  = (const float*)d_in[12];
    const float* ub2  = (const float*)d_in[13];
    float* h = (float*)d_out;

    int N = in_sizes[3];      // depth array
    int E = in_sizes[1] / 2;  // edge_index [2,E]

    char* ws = (char*)d_ws;
    size_t o = 0;
    auto alloc = [&](size_t bytes) -> char* {
        char* p = ws + o;
        o += (bytes + 255) & ~(size_t)255;
        return p;
    };
    f16*   t     = (f16*)alloc((size_t)N * 128 * 2);
    f16*   agg   = (f16*)alloc((size_t)N * 128 * 2);
    // degv, cur, dcnt contiguous -> one memset
    char*  z0    = (char*)alloc(0);
    int*   degv  = (int*)alloc((size_t)N * 4);
    int*   cur   = (int*)alloc((size_t)N * 4);
    int*   dcnt  = (int*)alloc(64);
    size_t zbytes = (size_t)((char*)alloc(0) - z0);
    int*   rowp  = (int*)alloc((size_t)(N + 1) * 4);
    int*   bsum  = (int*)alloc((size_t)((N + 255) / 256) * 4);
    int*   esrc  = (int*)alloc((size_t)E * 4);
    float* eso   = (float*)alloc((size_t)E * 4);
    int*   dlist = (int*)alloc((size_t)4 * N * 4);
    f16*   pwp   = (f16*)alloc(128 * 128 * 2);
    f16*   mw1p  = (f16*)alloc(128 * 128 * 2);
    f16*   mw2p  = (f16*)alloc(128 * 128 * 2);
    f16*   uw1p  = (f16*)alloc(256 * 128 * 2);
    f16*   uw2p  = (f16*)alloc(128 * 128 * 2);

    hipMemsetAsync(z0, 0, zbytes, stream);

    int CB = (E + 255) / 256;   // count blocks
    int NB = (N + 255) / 256;   // node-classify / scan blocks
    int SB = NB;
    int PB = (N + 63) / 64;     // proj blocks

    k_prep<<<48 + CB + NB, 256, 0, stream>>>(pw, mw1, mw2, uw1, uw2,
                                             pwp, mw1p, mw2p, uw1p, uw2p,
                                             ei, degv, dep, dcnt, dlist, CB, E, N);
    k_mid<<<SB + PB, 256, 0, stream>>>(degv, bsum, SB, x, pwp, mw1p, pb, mb1, h, t, N);
    k_scanC<<<NB, 256, 0, stream>>>(degv, bsum, rowp, N, E);
    k_scatter<<<CB, 256, 0, stream>>>(ei, eatt, rowp, cur, esrc, eso, E);

    for (int d = 1; d <= 4; d++) {
        k_msg<<<1024, 256, 0, stream>>>(t, mw1, mb2, mw2p, rowp, esrc, eso,
                                        dlist, dcnt, d - 1, agg, N);
        k_upd<<<512, 256, 0, stream>>>(h, t, agg, uw1p, uw2p, mw1p, ub1, ub2,
                                       mb1, dlist, dcnt, d - 1, N);
    }
}